// Round 2
// baseline (873.268 us; speedup 1.0000x reference)
//
#include <hip/hip_runtime.h>

// Correlation layer: out[b, dh*9+dw, h, w] =
//   (1/196) * sum_c in1[b,c,h,w] * in2[b,c, refl(h+dh-4), refl(w+dw-4)]
// in1,in2 = [8,196,128,224] f32 ; out = [8,81,128,224] f32
//
// v3: fully-prefetched round pipeline. Per round (KC=2 channels):
//   1. ds_write reg-staged tile (round r+1 data) into the other LDS buffer
//   2. issue global loads for round r+2 into regs (EARLY -> hidden by compute;
//      the compiler's vmcnt(0) drain at the barrier lands after compute)
//   3. compute: pure LDS reads + FMA (in1 is ALSO LDS-staged now -- it is one
//      row/channel shared by all 9 dh groups; was 9x redundant global, in-round)
//   4. one barrier
// XCD swizzle softened to 16-block chunks (16-way row sharing per L2 without
// the 128-block single-L2 hotspot of v2).

constexpr int NB = 8, NC = 196, NH = 128, NW = 224;
constexpr int ND = 9;
constexpr int PADV = 4;
constexpr int WS = 236;              // staged in2 row stride (floats)
constexpr int KC = 2;                // channels per round
constexpr int NSLOT = 56;            // w-groups of 4
constexpr int ACTIVE = ND * NSLOT;   // 504 compute threads
constexpr int TPB = 512;
constexpr int HWSZ = NH * NW;        // 28672
constexpr int NR = NC / KC;          // 98 rounds
constexpr int NBLK = NB * NH;        // 1024
constexpr int NXCD = 8;
constexpr int CHUNK = 16;            // consecutive bh per XCD chunk

constexpr int IN2SZ  = KC * ND * WS;        // 4248 floats per buffer
constexpr int IN1OFF = IN2SZ;               // in1 region offset in buffer
constexpr int SSZ    = IN2SZ + KC * NW;     // 4696 floats per buffer

constexpr int NVEC2 = KC * ND * NSLOT;      // 1008 in2 interior float4 slots
constexpr int NVEC  = NVEC2 + KC * NSLOT;   // + 112 in1 float4 slots = 1120
constexpr int NEDGE = KC * ND * 8;          // 144 in2 edge scalars

__device__ __forceinline__ int refl(int v, int n) {
    v = v < 0 ? -v : v;
    return v >= n ? 2 * n - 2 - v : v;
}

__global__ __launch_bounds__(TPB, 4)
void corr_kernel(const float* __restrict__ in1,
                 const float* __restrict__ in2,
                 float* __restrict__ out)
{
    __shared__ __align__(16) float s_stage[2][SSZ];   // 37,568 B

    const int tid = threadIdx.x;
    // chunked XCD swizzle: XCD x = blockIdx%8 owns chunks {x, 8+x, ...} of 16
    // consecutive bh -> 16 blocks share in2 rows inside one L2.
    const int ib = blockIdx.x;
    const int xc = ib & (NXCD - 1);
    const int jb = ib >> 3;                       // 0..127
    const int bh = ((jb >> 4) * NXCD + xc) * CHUNK + (jb & (CHUNK - 1));
    const int b  = bh / NH;
    const int h  = bh - b * NH;

    // ---- staging slot precompute (fixed across rounds; round adds c*HWSZ) ----
    // vector slots v in [0,1120): v<1008 -> in2 interior (cc,dh,g); else in1 (cc,g)
    const float* gA[3];
    int  lA[3];
    bool vA[3];
#pragma unroll
    for (int k = 0; k < 3; ++k) {
        int v  = tid + k * TPB;
        vA[k]  = v < NVEC;
        int vv = vA[k] ? v : 0;
        if (vv < NVEC2) {
            int cc = vv / (ND * NSLOT);
            int r  = vv - cc * (ND * NSLOT);
            int dh = r / NSLOT;
            int g  = r - dh * NSLOT;
            int y  = refl(h + dh - PADV, NH);
            gA[k]  = in2 + ((b * NC + cc) * NH + y) * NW + 4 * g;
            lA[k]  = (cc * ND + dh) * WS + 4 + 4 * g;
        } else {
            int u  = vv - NVEC2;
            int cc = u / NSLOT;
            int g  = u - cc * NSLOT;
            gA[k]  = in1 + ((b * NC + cc) * NH + h) * NW + 4 * g;
            lA[k]  = IN1OFF + cc * NW + 4 * g;
        }
    }
    // edge scalars: e<4: s=e, x=4-e ; e>=4: s=224+e, x=226-e
    const float* gB = in2;
    int  lB = 0;
    const bool vB = tid < NEDGE;
    {
        int v  = vB ? tid : 0;
        int cc = v / (ND * 8);
        int r  = v - cc * (ND * 8);
        int dh = r / 8;
        int e  = r - dh * 8;
        int s  = e < 4 ? e : 224 + e;
        int x  = e < 4 ? 4 - e : 226 - e;
        int y  = refl(h + dh - PADV, NH);
        gB = in2 + ((b * NC + cc) * NH + y) * NW + x;
        lB = (cc * ND + dh) * WS + s;
    }

    // ---- compute identity (dh-major) ----
    const int  cdh  = tid / NSLOT;          // 0..8
    const int  slot = tid - cdh * NSLOT;    // 0..55
    const int  w0   = slot * 4;
    const bool compute = tid < ACTIVE;

    float acc[ND][4];
#pragma unroll
    for (int d = 0; d < ND; ++d)
#pragma unroll
        for (int p = 0; p < 4; ++p) acc[d][p] = 0.f;

    const int STEP = KC * HWSZ;             // per-round channel advance (floats)

    // ---- prologue: stage round 0 into buf0; leave round 1 in regs ----
    float4 bufA[3];
    float  bufB = 0.f;
#pragma unroll
    for (int k = 0; k < 3; ++k)
        if (vA[k]) bufA[k] = *(const float4*)(gA[k]);
    if (vB) bufB = gB[0];
    {
        float* dst = &s_stage[0][0];
#pragma unroll
        for (int k = 0; k < 3; ++k)
            if (vA[k]) *(float4*)(dst + lA[k]) = bufA[k];
        if (vB) dst[lB] = bufB;
    }
#pragma unroll
    for (int k = 0; k < 3; ++k)
        if (vA[k]) bufA[k] = *(const float4*)(gA[k] + STEP);
    if (vB) bufB = gB[STEP];
    __syncthreads();

    // ---- main loop: one barrier per round, loads issued BEFORE compute ----
    for (int r = 0; r < NR; ++r) {
        const int cur = r & 1;
        const float* curb = &s_stage[cur][0];

        if (r + 1 < NR) {
            // stage round r+1 (regs loaded at round r-1) into the other buffer
            float* nxt = &s_stage[cur ^ 1][0];
#pragma unroll
            for (int k = 0; k < 3; ++k)
                if (vA[k]) *(float4*)(nxt + lA[k]) = bufA[k];
            if (vB) nxt[lB] = bufB;
            // issue round r+2 global loads NOW; barrier drain comes after compute
            if (r + 2 < NR) {
                const int off = (r + 2) * STEP;
#pragma unroll
                for (int k = 0; k < 3; ++k)
                    if (vA[k]) bufA[k] = *(const float4*)(gA[k] + off);
                if (vB) bufB = gB[off];
            }
        }

        if (compute) {
#pragma unroll
            for (int cc = 0; cc < KC; ++cc) {
                const float* wrow = curb + (cc * ND + cdh) * WS + w0;
                float4 wv0 = *(const float4*)(wrow);
                float4 wv1 = *(const float4*)(wrow + 4);
                float4 wv2 = *(const float4*)(wrow + 8);
                float4 a   = *(const float4*)(curb + IN1OFF + cc * NW + w0);
                const float wn[12] = {wv0.x, wv0.y, wv0.z, wv0.w,
                                      wv1.x, wv1.y, wv1.z, wv1.w,
                                      wv2.x, wv2.y, wv2.z, wv2.w};
#pragma unroll
                for (int d = 0; d < ND; ++d) {
                    acc[d][0] += a.x * wn[d + 0];
                    acc[d][1] += a.y * wn[d + 1];
                    acc[d][2] += a.z * wn[d + 2];
                    acc[d][3] += a.w * wn[d + 3];
                }
            }
        }
        __syncthreads();
    }

    if (compute) {
        const float scale = 1.0f / 196.0f;
#pragma unroll
        for (int d = 0; d < ND; ++d) {
            float4 o;
            o.x = acc[d][0] * scale;
            o.y = acc[d][1] * scale;
            o.z = acc[d][2] * scale;
            o.w = acc[d][3] * scale;
            float* op = out + (((b * (ND * ND)) + cdh * ND + d) * NH + h) * NW + w0;
            *(float4*)op = o;
        }
    }
}

extern "C" void kernel_launch(void* const* d_in, const int* in_sizes, int n_in,
                              void* d_out, int out_size, void* d_ws, size_t ws_size,
                              hipStream_t stream)
{
    const float* in1 = (const float*)d_in[0];
    const float* in2 = (const float*)d_in[1];
    float* outp = (float*)d_out;
    dim3 grid(NBLK);
    dim3 block(TPB);
    hipLaunchKernelGGL(corr_kernel, grid, block, 0, stream, in1, in2, outp);
}